// Round 1
// baseline (580.027 us; speedup 1.0000x reference)
//
#include <hip/hip_runtime.h>
#include <cstdint>

// Problem constants
#define BB   8
#define CC   19
#define HWP  524288          // H*W pixels per batch row
#define NPIX 4194304         // B*H*W
#define KSEL 131072          // int(0.25 * HWP)

// ws layout (bytes):
//   [0, 16777216)               loss float[NPIX]
//   CTRL region (zeroed each launch):
//     hist1 : 8*2048 u32
//     hist2 : 8*4096 u32
//     hist3 : 8*256  u32
//     sel1,cnt1,sel2,cnt2 : 8 u32 each
//     sumAbove : 8 double
#define CTRL_OFF 16777216
#define CTRL_WORDS (8*2048 + 8*4096 + 8*256 + 32 + 16)

__global__ void zero_u32(uint32_t* __restrict__ p, int n) {
    int i = blockIdx.x * 256 + threadIdx.x;
    if (i < n) p[i] = 0u;
}

// K1: fused CE-loss + 12-bit-prefix histogram.
// grid 4096 x 256; each thread handles 4 consecutive pixels (float4).
__global__ __launch_bounds__(256) void loss_hist1(
    const float* __restrict__ logits, const int* __restrict__ labels,
    float* __restrict__ loss, uint32_t* __restrict__ hist1)
{
    __shared__ uint32_t lh[2048];
    for (int i = threadIdx.x; i < 2048; i += 256) lh[i] = 0u;
    __syncthreads();

    int b = blockIdx.x >> 9;                       // 512 blocks per batch row
    int pix0 = blockIdx.x * 1024 + threadIdx.x * 4;
    int prow = pix0 & (HWP - 1);

    const float4* lg = (const float4*)(logits + (size_t)b * CC * HWP + prow);
    float4 a[CC];
#pragma unroll
    for (int c = 0; c < CC; c++) a[c] = lg[(size_t)c * (HWP / 4)];

    int4 lab = *(const int4*)(labels + pix0);

    float mx0 = a[0].x, mx1 = a[0].y, mx2 = a[0].z, mx3 = a[0].w;
#pragma unroll
    for (int c = 1; c < CC; c++) {
        mx0 = fmaxf(mx0, a[c].x); mx1 = fmaxf(mx1, a[c].y);
        mx2 = fmaxf(mx2, a[c].z); mx3 = fmaxf(mx3, a[c].w);
    }
    float g0 = 0.f, g1 = 0.f, g2 = 0.f, g3 = 0.f;
    float e0 = 0.f, e1 = 0.f, e2 = 0.f, e3 = 0.f;
#pragma unroll
    for (int c = 0; c < CC; c++) {
        e0 += __expf(a[c].x - mx0); e1 += __expf(a[c].y - mx1);
        e2 += __expf(a[c].z - mx2); e3 += __expf(a[c].w - mx3);
        g0 = (lab.x == c) ? a[c].x : g0;
        g1 = (lab.y == c) ? a[c].y : g1;
        g2 = (lab.z == c) ? a[c].z : g2;
        g3 = (lab.w == c) ? a[c].w : g3;
    }
    // CE is mathematically >= 0; clamp guards the histogram against a
    // rounding fluke producing a tiny negative (sign bit would corrupt bins).
    float l0 = fmaxf(mx0 + __logf(e0) - g0, 0.f);
    float l1 = fmaxf(mx1 + __logf(e1) - g1, 0.f);
    float l2 = fmaxf(mx2 + __logf(e2) - g2, 0.f);
    float l3 = fmaxf(mx3 + __logf(e3) - g3, 0.f);

    float4 o; o.x = l0; o.y = l1; o.z = l2; o.w = l3;
    *(float4*)(loss + pix0) = o;

    atomicAdd(&lh[__float_as_uint(l0) >> 20], 1u);
    atomicAdd(&lh[__float_as_uint(l1) >> 20], 1u);
    atomicAdd(&lh[__float_as_uint(l2) >> 20], 1u);
    atomicAdd(&lh[__float_as_uint(l3) >> 20], 1u);

    __syncthreads();
    for (int i = threadIdx.x; i < 2048; i += 256) {
        uint32_t v = lh[i];
        if (v) atomicAdd(&hist1[b * 2048 + i], v);
    }
}

// Generic descending scan over a per-row histogram. 8 blocks x 64 lanes.
// Finds bucket sel such that countAbove(sel) < target <= countAbove(sel)+h[sel].
// cntOut = prev + countAbove(sel)  (cumulative strictly-greater count).
__global__ void scan_hist(const uint32_t* __restrict__ hist, int nbins,
                          const uint32_t* __restrict__ cntPrev,
                          uint32_t* __restrict__ selOut, uint32_t* __restrict__ cntOut)
{
    int r = blockIdx.x;
    int lane = threadIdx.x & 63;
    int chunk = nbins >> 6;
    const uint32_t* hrow = hist + r * nbins;
    int base = nbins - chunk * (lane + 1);   // lane 0 owns the TOP bins

    uint32_t csum = 0;
    for (int i = 0; i < chunk; i++) csum += hrow[base + i];

    uint32_t inc = csum;
    for (int off = 1; off < 64; off <<= 1) {
        uint32_t t = __shfl_up(inc, off);
        if (lane >= off) inc += t;
    }
    uint32_t pre = inc - csum;               // count in all chunks above mine

    uint32_t prev = cntPrev ? cntPrev[r] : 0u;
    uint32_t target = (uint32_t)KSEL - prev;

    if (pre < target && pre + csum >= target) {
        uint32_t cum = pre;
        for (int i = chunk - 1; i >= 0; i--) {
            uint32_t h = hrow[base + i];
            if (cum + h >= target) {
                selOut[r] = (uint32_t)(base + i);
                cntOut[r] = prev + cum;
                break;
            }
            cum += h;
        }
    }
}

__device__ __forceinline__ void block_sum_atomic(double sum, double* dst) {
    __shared__ double wsum[4];
    int lane = threadIdx.x & 63, wid = threadIdx.x >> 6;
    for (int off = 32; off > 0; off >>= 1) sum += __shfl_down(sum, off);
    if (lane == 0) wsum[wid] = sum;
    __syncthreads();
    if (threadIdx.x == 0) {
        double t = wsum[0] + wsum[1] + wsum[2] + wsum[3];
        if (t != 0.0) atomicAdd(dst, t);
    }
}

// K3: sum values strictly above bucket sel1; 12-bit mid histogram inside sel1.
__global__ __launch_bounds__(256) void refine2(
    const float* __restrict__ loss, uint32_t* __restrict__ hist2,
    const uint32_t* __restrict__ sel1, double* __restrict__ sumAbove)
{
    __shared__ uint32_t lh[4096];
    for (int i = threadIdx.x; i < 4096; i += 256) lh[i] = 0u;
    __syncthreads();

    int b = blockIdx.x >> 9;
    uint32_t s1 = sel1[b];
    int pix0 = blockIdx.x * 1024 + threadIdx.x * 4;
    float4 v = *(const float4*)(loss + pix0);

    double sum = 0.0;
    {
        float vv[4] = {v.x, v.y, v.z, v.w};
#pragma unroll
        for (int j = 0; j < 4; j++) {
            uint32_t u = __float_as_uint(vv[j]);
            uint32_t t = u >> 20;
            if (t > s1) sum += (double)vv[j];
            else if (t == s1) atomicAdd(&lh[(u >> 8) & 0xFFFu], 1u);
        }
    }
    __syncthreads();   // ensure all LDS hist updates done before flush
    block_sum_atomic(sum, &sumAbove[b]);
    for (int i = threadIdx.x; i < 4096; i += 256) {
        uint32_t c = lh[i];
        if (c) atomicAdd(&hist2[b * 4096 + i], c);
    }
}

// K5: sum values in (sel1, mid > sel2); 8-bit low histogram at (sel1, sel2).
__global__ __launch_bounds__(256) void refine3(
    const float* __restrict__ loss, uint32_t* __restrict__ hist3,
    const uint32_t* __restrict__ sel1, const uint32_t* __restrict__ sel2,
    double* __restrict__ sumAbove)
{
    __shared__ uint32_t lh[256];
    lh[threadIdx.x] = 0u;
    __syncthreads();

    int b = blockIdx.x >> 9;
    uint32_t s1 = sel1[b], s2 = sel2[b];
    int pix0 = blockIdx.x * 1024 + threadIdx.x * 4;
    float4 v = *(const float4*)(loss + pix0);

    double sum = 0.0;
    {
        float vv[4] = {v.x, v.y, v.z, v.w};
#pragma unroll
        for (int j = 0; j < 4; j++) {
            uint32_t u = __float_as_uint(vv[j]);
            if ((u >> 20) == s1) {
                uint32_t mid = (u >> 8) & 0xFFFu;
                if (mid > s2) sum += (double)vv[j];
                else if (mid == s2) atomicAdd(&lh[u & 0xFFu], 1u);
            }
        }
    }
    __syncthreads();
    block_sum_atomic(sum, &sumAbove[b]);
    {
        uint32_t c = lh[threadIdx.x];
        if (c) atomicAdd(&hist3[b * 256 + threadIdx.x], c);
    }
}

// Finalize: bins of hist3 correspond to EXACT float bit patterns, so the
// tie-corrected top-k sum is closed-form. 1 block, threads 0..7 = rows.
__global__ void finalize(const uint32_t* __restrict__ hist3,
                         const uint32_t* __restrict__ sel1,
                         const uint32_t* __restrict__ sel2,
                         const uint32_t* __restrict__ cnt2,
                         const double* __restrict__ sumAbove,
                         float* __restrict__ out)
{
    __shared__ double rs[8];
    int t = threadIdx.x;
    if (t < 8) {
        int r = t;
        uint32_t rem = (uint32_t)KSEL - cnt2[r];
        double sum = sumAbove[r];
        uint32_t P = (sel1[r] << 20) | (sel2[r] << 8);
        for (int c = 255; c >= 0; c--) {
            uint32_t h = hist3[r * 256 + c];
            if (!h) continue;
            double val = (double)__uint_as_float(P | (uint32_t)c);
            if (h >= rem) { sum += (double)rem * val; rem = 0; break; }
            sum += (double)h * val;
            rem -= h;
        }
        rs[r] = sum;
    }
    __syncthreads();
    if (t == 0) {
        double tot = 0.0;
        for (int i = 0; i < 8; i++) tot += rs[i];
        out[0] = (float)(tot / ((double)BB * (double)KSEL));
    }
}

extern "C" void kernel_launch(void* const* d_in, const int* in_sizes, int n_in,
                              void* d_out, int out_size, void* d_ws, size_t ws_size,
                              hipStream_t stream)
{
    const float* logits = (const float*)d_in[0];
    const int* labels   = (const int*)d_in[1];
    float* out          = (float*)d_out;

    char* ws = (char*)d_ws;
    float* loss      = (float*)ws;
    uint32_t* hist1  = (uint32_t*)(ws + CTRL_OFF);
    uint32_t* hist2  = hist1 + 8 * 2048;
    uint32_t* hist3  = hist2 + 8 * 4096;
    uint32_t* sel1   = hist3 + 8 * 256;
    uint32_t* cnt1   = sel1 + 8;
    uint32_t* sel2   = cnt1 + 8;
    uint32_t* cnt2   = sel2 + 8;
    double* sumAbove = (double*)(cnt2 + 8);   // 8-byte aligned (offset 204928 from CTRL_OFF)

    zero_u32<<<(CTRL_WORDS + 255) / 256, 256, 0, stream>>>(hist1, CTRL_WORDS);
    loss_hist1<<<4096, 256, 0, stream>>>(logits, labels, loss, hist1);
    scan_hist<<<8, 64, 0, stream>>>(hist1, 2048, nullptr, sel1, cnt1);
    refine2<<<4096, 256, 0, stream>>>(loss, hist2, sel1, sumAbove);
    scan_hist<<<8, 64, 0, stream>>>(hist2, 4096, cnt1, sel2, cnt2);
    refine3<<<4096, 256, 0, stream>>>(loss, hist3, sel1, sel2, sumAbove);
    finalize<<<1, 64, 0, stream>>>(hist3, sel1, sel2, cnt2, sumAbove, out);
}